// Round 3
// baseline (654.852 us; speedup 1.0000x reference)
//
#include <hip/hip_runtime.h>
#include <stddef.h>

#define TT 2048
#define NN 4096
#define LSEG 64
#define NSEG (TT / LSEG)   // 32
#define NBLK 16            // phase A1 blocks, ONE WAVE each
#define TPA 64             // phase A1/A2 threads per block (= 1 wave)
#define NPT 4              // neurons per thread in A1 (NBLK*TPA*NPT == NN)
#define TPB 256
#define WCAP 256           // fire-list capacity (>= max_spikes)
#define MAXU 0xFFFFFFFFu
#define NOFIRE 0xFFFFFFFEu

// ---------------- Phase A1: exact coupled sim, events-only, lag-2 pipeline ----------
// 16 blocks x 64 threads, 4 neurons/thread, state in registers. NO ys writes.
// Outputs ONLY: fire schedule (fireT/fireIdx, <=maxs entries), t_stop, nsp -> hdr.
// Lag-2 schedule (bit-exact; only the timing of each exact computation moves):
//   iter t: P0 poll row t-2   (published 1.4 iters ago -> usually first-attempt hit)
//              -> exact fire(t-2); issue gather w[gm(t-2)] (consumed iter t+1)
//              -> immediate break when nsp hits maxs (t_stop closed-form)
//           P2 resolve i(t-2) w/ gather gm(t-3) (issued a full iter ago);
//              drift+transition step t-2 in reference op order -> V(t-1)
//           P3 ev(t-1) from V(t-1); publish block-min to slots[t-1]
//           P4 prefetch inp/ru row t-1 (consumed iter t+1)
// vmcnt queue at P0's poll contains only: last iter's publish (acked), last
// iter's prefetch (~1 iter old) -> poll attempts are near-clean.
__global__ __launch_bounds__(TPA) void phaseA1(
    const float* __restrict__ ts, const float* __restrict__ inp,
    const float* __restrict__ w, const float* __restrict__ v0,
    const float* __restrict__ i0, const float* __restrict__ mu,
    const float* __restrict__ s0u, const float* __restrict__ ru,
    const int* __restrict__ mx, unsigned int* __restrict__ hdr,
    unsigned int* __restrict__ slots, unsigned int* __restrict__ fireT,
    unsigned int* __restrict__ fireIdx)
{
#pragma clang fp contract(off)
  const int tid = threadIdx.x;              // 0..63
  const int blk = blockIdx.x;               // 0..15
  const int idx4 = blk * TPA + tid;         // float4 index within a row (NN/4)
  const int n0 = idx4 * NPT;                // first neuron id of this thread
  const float dt = ts[1] - ts[0];
  const float mu1 = mu[0], mu2 = mu[1];
  const int maxs = mx[0];

  const float4* inp4 = (const float4*)inp;
  const float4* ru4  = (const float4*)ru;
  const float4* w4   = (const float4*)w;

  float4 a4;
  a4 = ((const float4*)v0)[idx4];  float v[NPT]    = {a4.x, a4.y, a4.z, a4.w};
  a4 = ((const float4*)i0)[idx4];  float i_nw[NPT] = {a4.x, a4.y, a4.z, a4.w};
  a4 = ((const float4*)s0u)[idx4];
  float s[NPT] = {logf(a4.x + 1e-12f) - 0.01f, logf(a4.y + 1e-12f) - 0.01f,
                  logf(a4.z + 1e-12f) - 0.01f, logf(a4.w + 1e-12f) - 0.01f};

  float snP[NPT] = {0.f, 0.f, 0.f, 0.f};           // s_n(t-2) entering iter t
  bool  evP[NPT] = {false, false, false, false};   // ev(t-2) entering iter t
  bool  aw[NPT]  = {false, false, false, false};   // w-add pending from fire(t-3)
  float wvP[NPT] = {0.f, 0.f, 0.f, 0.f};           // w[gm(t-3)] (issued iter t-1)
  float4 inp_cur = make_float4(0.f,0.f,0.f,0.f);   // inp row t-2
  float4 ru_cur  = make_float4(0.f,0.f,0.f,0.f);   // ru  row t-2
  int nsp = 0;                                     // fires through step t-3
  int t_stop = TT;
  bool pubPrev = false;                            // row t-2 was published

  for (int t = 0;; ++t) {
    bool  fire2 = false;                           // fire(t-2)
    bool  awN[NPT] = {false, false, false, false};
    float wN[NPT]  = {0.f, 0.f, 0.f, 0.f};

    // ---- P0: poll row t-2; exact fire(t-2); gather; immediate termination
    if (t >= 2) {
      unsigned int gm2 = NOFIRE;
      if (pubPrev) {
        const unsigned int* row = &slots[(size_t)(t - 2) * NBLK];
        unsigned int x = MAXU;
        long g = 0;
        for (;;) {
          x = __hip_atomic_load(&row[tid & (NBLK - 1)], __ATOMIC_RELAXED,
                                __HIP_MEMORY_SCOPE_AGENT);
          if (__ballot(x != MAXU) == ~0ULL) break;
          if (++g > (1L << 20)) break;   // safety escape (bug -> wrong, not hang)
        }
        gm2 = x;
#pragma unroll
        for (int off = 1; off < NBLK; off <<= 1) {
          unsigned int o = (unsigned int)__shfl_xor((int)gm2, off, 64);
          gm2 = gm2 < o ? gm2 : o;
        }
      }
      fire2 = (gm2 < (unsigned int)NN) && (nsp < maxs);
      if (fire2) {
        if (blk == 0 && tid == 0 && nsp < WCAP) {
          fireT[nsp] = (unsigned int)(t - 2);
          fireIdx[nsp] = gm2;
        }
        // issue gather; consumed at iter t+1 P2 (full iteration of slack)
        float4 wr = w4[(size_t)gm2 * (NN / 4) + idx4];
        wN[0] = wr.x; wN[1] = wr.y; wN[2] = wr.z; wN[3] = wr.w;
#pragma unroll
        for (int k = 0; k < NPT; ++k) awN[k] = !evP[k];
        nsp += 1;
        if (nsp >= maxs) {   // closed-form t_stop: first L-multiple >= (t-2)+1
          t_stop = ((t - 1 + LSEG - 1) / LSEG) * LSEG;
          if (t_stop > TT) t_stop = TT;
          break;
        }
      }
      if (t - 1 == TT) { t_stop = TT; break; }   // full horizon simulated
    }

    // ---- P2: advance state to V(t-1) (drift+transition of step t-2)
    if (t >= 2) {
      float iv[NPT] = {inp_cur.x, inp_cur.y, inp_cur.z, inp_cur.w};
      float rv[NPT] = {ru_cur.x,  ru_cur.y,  ru_cur.z,  ru_cur.w};
#pragma unroll
      for (int k = 0; k < NPT; ++k) {
        float ifull = aw[k] ? (i_nw[k] + wvP[k]) : i_nw[k];   // fire(t-3) add
        float vn  = v[k] + dt * (mu1 * (ifull - v[k]) + mu1 * iv[k]);
        float in_ = ifull + dt * (-mu2 * ifull);
        if (evP[k] && fire2) {
          v[k] = vn - 1.0f;
          s[k] = logf(rv[k] + 1e-12f) - 0.01f;   // logf only on rare ev path
        } else {
          v[k] = vn; s[k] = snP[k];
        }
        i_nw[k] = in_;
      }
    }

    // ---- P3: ev(t-1) from V(t-1); publish block-min to slots[t-1]
    bool pubNow = false;
    bool evN[NPT] = {false, false, false, false};
    if (t >= 1) {
      unsigned int m = NOFIRE;
#pragma unroll
      for (int k = 0; k < NPT; ++k) {
        float sig = 1.0f / (1.0f + expf(-v[k]));
        float sn = s[k] + dt * sig;
        snP[k] = sn;
        bool e = sn >= 0.0f;
        evN[k] = e;
        unsigned int c = e ? (unsigned int)(n0 + k) : NOFIRE;
        m = m < c ? m : c;
      }
      // nsp(t-1) < maxs guaranteed here (immediate break above) -> always publish
#pragma unroll
      for (int off = 1; off < 64; off <<= 1) {
        unsigned int o = (unsigned int)__shfl_xor((int)m, off, 64);
        m = m < o ? m : o;
      }
      if (tid == 0)
        __hip_atomic_store(&slots[(size_t)(t - 1) * NBLK + blk], m,
                           __ATOMIC_RELAXED, __HIP_MEMORY_SCOPE_AGENT);
      pubNow = true;
    }

    // ---- P4: prefetch inp/ru row t-1 (consumed iter t+1 P2)
    float4 inw = make_float4(0.f,0.f,0.f,0.f);
    float4 rnw = make_float4(0.f,0.f,0.f,0.f);
    if (t >= 1 && t - 1 < TT) {
      inw = inp4[(size_t)(t - 1) * (NN / 4) + idx4];
      rnw = ru4[(size_t)(t - 1) * (NN / 4) + idx4];
    }

    // ---- P5: rotate pipeline registers
#pragma unroll
    for (int k = 0; k < NPT; ++k) {
      evP[k] = evN[k]; aw[k] = awN[k]; wvP[k] = wN[k];
    }
    inp_cur = inw; ru_cur = rnw;
    pubPrev = pubNow;
  }

  if (blk == 0 && tid == 0) {
    hdr[0] = (unsigned int)t_stop;
    hdr[1] = (unsigned int)nsp;
  }
}

// ---------------- Phase A2: parallel replay of [0, K') with known schedule -------
// 64 blocks x 64 threads, 1 neuron/thread. Fire times/indices known ahead ->
// pre-gather all fired w values into LDS; inp/ru in 8-deep register rings.
// Identical expressions + fp contract(off) => bit-identical to A1's trajectory.
__global__ __launch_bounds__(TPA) void phaseA2(
    const float* __restrict__ ts, const float* __restrict__ inp,
    const float* __restrict__ w, const float* __restrict__ v0,
    const float* __restrict__ i0, const float* __restrict__ mu,
    const float* __restrict__ s0u, const float* __restrict__ ru,
    const unsigned int* __restrict__ hdr, const unsigned int* __restrict__ fireT,
    const unsigned int* __restrict__ fireIdx, float* __restrict__ ys)
{
#pragma clang fp contract(off)
  const int tid = threadIdx.x;
  const int n = blockIdx.x * TPA + tid;
  const int Kp = (int)hdr[0];
  int nf = (int)hdr[1]; if (nf > WCAP) nf = WCAP;
  const float dt = ts[1] - ts[0];
  const float mu1 = mu[0], mu2 = mu[1];

  __shared__ unsigned int sT[WCAP];
  __shared__ float wlds[WCAP][TPA];
  for (int k = tid; k < nf; k += TPA) sT[k] = fireT[k];
  // batched-8 pre-gather of fired w rows (loads pipelined within a batch)
  for (int k0 = 0; k0 < nf; k0 += 8) {
    float tmp[8];
#pragma unroll
    for (int j = 0; j < 8; ++j) {
      int k = k0 + j;
      tmp[j] = (k < nf) ? w[(size_t)fireIdx[k] * NN + n] : 0.0f;
    }
#pragma unroll
    for (int j = 0; j < 8; ++j) {
      int k = k0 + j;
      if (k < nf) wlds[k][tid] = tmp[j];
    }
  }
  __syncthreads();

  float v = v0[n];
  float i = i0[n];
  float s = logf(s0u[n] + 1e-12f) - 0.01f;

  float ib[8], rb[8];
#pragma unroll
  for (int j = 0; j < 8; ++j) {
    ib[j] = inp[(size_t)j * NN + n];
    rb[j] = ru[(size_t)j * NN + n];
  }
  int kp = 0;
  for (int tb = 0; tb < Kp; tb += 8) {    // Kp is a multiple of 64 -> no tail
#pragma unroll
    for (int j = 0; j < 8; ++j) {
      const int t = tb + j;
      const float x   = ib[j];
      const float ruv = rb[j];
      if (t + 8 < Kp) {                   // 8-deep prefetch ring (static idx)
        ib[j] = inp[(size_t)(t + 8) * NN + n];
        rb[j] = ru[(size_t)(t + 8) * NN + n];
      }
      float sig = 1.0f / (1.0f + expf(-v));
      float sn = s + dt * sig;
      bool e = sn >= 0.0f;
      float vn  = v + dt * (mu1 * (i - v) + mu1 * x);
      float in_ = i + dt * (-mu2 * i);
      bool fire = (kp < nf) && (sT[kp] == (unsigned int)t);
      if (fire) {
        float wc = wlds[kp][tid];
        ++kp;
        if (e) { v = vn - 1.0f; i = in_;      s = logf(ruv + 1e-12f) - 0.01f; }
        else   { v = vn;        i = in_ + wc; s = sn; }
      } else   { v = vn;        i = in_;      s = sn; }
      size_t o = ((size_t)t * NN + n) * 3;
      *(float3*)(ys + o) = make_float3(v, i, s);
    }
  }
}

// ---------------- Phase B: decoupled closed-form tail (unchanged) ----------------
// P1: per (neuron, segment): C = sum_j a^(L-1-j) * b * (i_j + inp_j), i_j geometric.
__global__ __launch_bounds__(TPB) void p1_segc(
    const float* __restrict__ ts, const float* __restrict__ inp,
    const float* __restrict__ mu, const float* __restrict__ ys,
    const unsigned int* __restrict__ hdr, float* __restrict__ buf1)
{
  unsigned int Kp = hdr[0];
  unsigned int g0 = Kp / LSEG;
  unsigned int g = blockIdx.x >> 4;
  if (g < g0) return;
  int n = (blockIdx.x & 15) * TPB + threadIdx.x;
  float dt = ts[1] - ts[0];
  float mu1 = mu[0], mu2 = mu[1];
  float a = 1.0f - dt * mu1, b = dt * mu1, r = 1.0f - dt * mu2;
  float ibase = ys[((size_t)(Kp - 1) * NN + n) * 3 + 1];
  float ij = ibase * powf(r, (float)((int)(g * LSEG) - (int)Kp));
  float c = 0.0f;
  size_t base = (size_t)(g * LSEG) * NN + n;
  for (int j = 0; j < LSEG; ++j) {
    float x = inp[base + (size_t)j * NN];
    c = a * c + b * (ij + x);
    ij *= r;
  }
  buf1[(size_t)g * NN + n] = c;
}

// P2: per neuron, scan segment-boundary v:  v_{g+1} = a^L v_g + C_g (in place -> Vb)
__global__ __launch_bounds__(TPB) void p2_scanv(
    const float* __restrict__ ts, const float* __restrict__ mu,
    const float* __restrict__ ys, const unsigned int* __restrict__ hdr,
    float* __restrict__ buf1)
{
  unsigned int Kp = hdr[0];
  unsigned int g0 = Kp / LSEG;
  if (g0 >= NSEG) return;
  int n = blockIdx.x * TPB + threadIdx.x;
  float dt = ts[1] - ts[0];
  float mu1 = mu[0];
  float a = 1.0f - dt * mu1;
  float aL = a;
  for (int k = 0; k < 6; ++k) aL *= aL;   // a^64
  float v = ys[((size_t)(Kp - 1) * NN + n) * 3 + 0];
  for (unsigned int g = g0; g < NSEG; ++g) {
    float cg = buf1[(size_t)g * NN + n];
    buf1[(size_t)g * NN + n] = v;
    v = aL * v + cg;
  }
}

// P3: per (neuron, segment): replay 64 steps; write v,i and local s-prefix to ys;
// stash segment sigma-sum into buf2.
__global__ __launch_bounds__(TPB) void p3_seg(
    const float* __restrict__ ts, const float* __restrict__ inp,
    const float* __restrict__ mu, const unsigned int* __restrict__ hdr,
    const float* __restrict__ buf1, float* __restrict__ buf2,
    float* __restrict__ ys)
{
  unsigned int Kp = hdr[0];
  unsigned int g0 = Kp / LSEG;
  unsigned int g = blockIdx.x >> 4;
  if (g < g0) return;
  int n = (blockIdx.x & 15) * TPB + threadIdx.x;
  float dt = ts[1] - ts[0];
  float mu1 = mu[0], mu2 = mu[1];
  float r = 1.0f - dt * mu2;
  float v = buf1[(size_t)g * NN + n];
  float ibase = ys[((size_t)(Kp - 1) * NN + n) * 3 + 1];
  float i = ibase * powf(r, (float)((int)(g * LSEG) - (int)Kp));
  float sl = 0.0f;
  for (int j = 0; j < LSEG; ++j) {
    size_t t = (size_t)g * LSEG + j;
    float x = inp[t * NN + n];
    float sig = 1.0f / (1.0f + expf(-v));
    sl = sl + dt * sig;
    float vn  = v + dt * (mu1 * (i - v) + mu1 * x);
    float in_ = i + dt * (-mu2 * i);
    size_t o = (t * NN + n) * 3;
    ys[o] = vn; ys[o + 1] = in_; ys[o + 2] = sl;
    v = vn; i = in_;
  }
  buf2[(size_t)g * NN + n] = sl;
}

// P4: per neuron, scan sigma-sums -> s at segment starts (in place -> Sb)
__global__ __launch_bounds__(TPB) void p4_scans(
    const float* __restrict__ ys, const unsigned int* __restrict__ hdr,
    float* __restrict__ buf2)
{
  unsigned int Kp = hdr[0];
  unsigned int g0 = Kp / LSEG;
  if (g0 >= NSEG) return;
  int n = blockIdx.x * TPB + threadIdx.x;
  float s = ys[((size_t)(Kp - 1) * NN + n) * 3 + 2];
  for (unsigned int g = g0; g < NSEG; ++g) {
    float t = buf2[(size_t)g * NN + n];
    buf2[(size_t)g * NN + n] = s;
    s += t;
  }
}

// P5: ys[t][n].s += Sb[t/L][n] for t >= K'
__global__ __launch_bounds__(TPB) void p5_fixs(
    const unsigned int* __restrict__ hdr, const float* __restrict__ buf2,
    float* __restrict__ ys)
{
  unsigned int Kp = hdr[0];
  size_t e = (size_t)Kp * NN + (size_t)blockIdx.x * TPB + threadIdx.x;
  if (e >= (size_t)TT * NN) return;
  unsigned int t = (unsigned int)(e >> 12);        // /NN
  unsigned int n = (unsigned int)(e & (NN - 1));
  unsigned int g = t >> 6;                         // /LSEG
  ys[e * 3 + 2] += buf2[(size_t)g * NN + n];
}

extern "C" void kernel_launch(void* const* d_in, const int* in_sizes, int n_in,
                              void* d_out, int out_size, void* d_ws, size_t ws_size,
                              hipStream_t stream)
{
  (void)in_sizes; (void)n_in; (void)out_size; (void)ws_size;
  const float* ts  = (const float*)d_in[0];
  const float* inp = (const float*)d_in[1];
  const float* w   = (const float*)d_in[2];
  const float* v0  = (const float*)d_in[3];
  const float* i0  = (const float*)d_in[4];
  const float* mu  = (const float*)d_in[5];
  const float* s0u = (const float*)d_in[6];
  const float* ru  = (const float*)d_in[7];
  const int*   mx  = (const int*)d_in[8];
  float* ys = (float*)d_out;

  char* wsb = (char*)d_ws;
  unsigned int* hdr     = (unsigned int*)wsb;               // 256 B
  unsigned int* fireT   = (unsigned int*)(wsb + 256);       // 1 KB (WCAP entries)
  unsigned int* fireIdx = (unsigned int*)(wsb + 1280);      // 1 KB
  unsigned int* slots   = (unsigned int*)(wsb + 4096);      // TT*16*4 = 128 KB
  float* buf1 = (float*)(wsb + 4096 + (size_t)TT * NBLK * 4);   // 512 KB
  float* buf2 = buf1 + (size_t)NSEG * NN;                       // 512 KB

  // barrier slots must start as 0xFFFFFFFF (= "not arrived")
  hipMemsetAsync(slots, 0xFF, (size_t)TT * NBLK * 4, stream);

  phaseA1<<<NBLK, TPA, 0, stream>>>(ts, inp, w, v0, i0, mu, s0u, ru, mx,
                                    hdr, slots, fireT, fireIdx);
  phaseA2<<<NN / TPA, TPA, 0, stream>>>(ts, inp, w, v0, i0, mu, s0u, ru,
                                        hdr, fireT, fireIdx, ys);
  p1_segc<<<NSEG * 16, TPB, 0, stream>>>(ts, inp, mu, ys, hdr, buf1);
  p2_scanv<<<NN / TPB, TPB, 0, stream>>>(ts, mu, ys, hdr, buf1);
  p3_seg<<<NSEG * 16, TPB, 0, stream>>>(ts, inp, mu, hdr, buf1, buf2, ys);
  p4_scans<<<NN / TPB, TPB, 0, stream>>>(ys, hdr, buf2);
  p5_fixs<<<(TT - 128) * NN / TPB, TPB, 0, stream>>>(hdr, buf2, ys);
}